// Round 4
// baseline (445.091 us; speedup 1.0000x reference)
//
#include <hip/hip_runtime.h>
#include <cstdint>

// Problem constants: B=4, N=2048, D=1024, H=16, HD=64, RD=32, K=1024
typedef unsigned short ushortT;
typedef unsigned int uintT;
typedef __attribute__((ext_vector_type(8))) short short8;
typedef __attribute__((ext_vector_type(8))) __bf16 bf16x8;
typedef __attribute__((ext_vector_type(4))) float floatx4;
typedef __attribute__((ext_vector_type(4))) unsigned int u32x4;
typedef __attribute__((ext_vector_type(2))) unsigned int u32x2;

__device__ __forceinline__ void gl_lds16(const void* g, void* l) {
    auto gp = reinterpret_cast<const __attribute__((address_space(1))) unsigned int*>(
        reinterpret_cast<uintptr_t>(g));
    auto lp = reinterpret_cast<__attribute__((address_space(3))) unsigned int*>(
        reinterpret_cast<uintptr_t>(l));
    __builtin_amdgcn_global_load_lds(gp, lp, 16, 0, 0);
}

__device__ __forceinline__ ushortT f2bf(float f) {  // RNE
    unsigned int u = __float_as_uint(f);
    u = (u + 0x7FFFu + ((u >> 16) & 1u)) >> 16;
    return (ushortT)u;
}
__device__ __forceinline__ ushortT f2bf_tr(float f) {  // truncate (P matrix only)
    return (ushortT)(__float_as_uint(f) >> 16);
}

__device__ __forceinline__ floatx4 mfma16(short8 a, short8 b, floatx4 c) {
    return __builtin_amdgcn_mfma_f32_16x16x32_bf16(
        __builtin_bit_cast(bf16x8, a), __builtin_bit_cast(bf16x8, b), c, 0, 0, 0);
}

// ---------------- fp32 -> bf16 for x_q and x_kv (grid 16384) --------------
__global__ void cvt_bf16_2(const float* __restrict__ a, const float* __restrict__ b,
                           ushortT* __restrict__ oa, ushortT* __restrict__ ob) {
    int bid = blockIdx.x;
    const float* in; ushortT* out;
    if (bid < 8192) { in = a; out = oa; } else { in = b; out = ob; bid -= 8192; }
    size_t i = ((size_t)bid * 256 + threadIdx.x) * 4;
    floatx4 v = *(const floatx4*)(in + i);
    u32x2 p;
    p[0] = (uintT)f2bf(v[0]) | ((uintT)f2bf(v[1]) << 16);
    p[1] = (uintT)f2bf(v[2]) | ((uintT)f2bf(v[3]) << 16);
    *(u32x2*)(out + i) = p;
}

// ---------------- W (1024x1024 fp32 [k][n]) -> Wt (bf16 [n][k]) -----------
__global__ void wtrans(const float* __restrict__ Wq, const float* __restrict__ Wk,
                       const float* __restrict__ Wv, const float* __restrict__ Wo,
                       ushortT* __restrict__ Tq, ushortT* __restrict__ Tk,
                       ushortT* __restrict__ Tv, ushortT* __restrict__ To) {
    __shared__ float T[64][65];
    const float* src; ushortT* dst;
    switch (blockIdx.z) {
        case 0: src = Wq; dst = Tq; break;
        case 1: src = Wk; dst = Tk; break;
        case 2: src = Wv; dst = Tv; break;
        default: src = Wo; dst = To; break;
    }
    const int t = threadIdx.x, lx = t & 63, ly0 = t >> 6;
    const int kt = blockIdx.y * 64, nt = blockIdx.x * 64;
#pragma unroll
    for (int i = 0; i < 16; ++i) {
        int ly = i * 4 + ly0;
        T[ly][lx] = src[(size_t)(kt + ly) * 1024 + nt + lx];
    }
    __syncthreads();
#pragma unroll
    for (int i = 0; i < 16; ++i) {
        int ly = i * 4 + ly0;
        dst[(size_t)(nt + ly) * 1024 + kt + lx] = f2bf(T[lx][ly]);
    }
}

// ======== shared GEMM core: 128x128 tile, BK=64, swizzled LDS =============
// LDS layout: X[row][64], 16B chunk c stores global chunk (c ^ (row&7)).
// Staged via gl_lds16 with the XOR folded into the GLOBAL address so the
// LDS destination stays lane-linear. Fragment reads are then 2-way = free.
#define GEMM_CORE(A_, B_)                                                        \
    const int t = threadIdx.x;                                                   \
    const int wave = t >> 6, lane = t & 63;                                      \
    const int quad = lane >> 4, l15 = lane & 15;                                 \
    const int wrow = (wave >> 1) * 64, wcol = (wave & 1) * 64;                   \
    floatx4 acc[4][4] = {};                                                      \
    const int srb = t >> 3;                                                      \
    const int schx = ((t & 7) ^ (srb & 7)) * 8;                                  \
    for (int kt = 0; kt < 16; ++kt) {                                            \
        const int k0 = kt * 64;                                                  \
        if (kt) __syncthreads();                                                 \
        _Pragma("unroll")                                                        \
        for (int p = 0; p < 4; ++p) {                                            \
            int row = p * 32 + srb;                                              \
            gl_lds16(A_ + (size_t)(mBase + row) * 1024 + k0 + schx,              \
                     &At[p * 2048 + t * 8]);                                     \
            gl_lds16(B_ + (size_t)(nBase + row) * 1024 + k0 + schx,              \
                     &Bt[p * 2048 + t * 8]);                                     \
        }                                                                        \
        __syncthreads();                                                         \
        _Pragma("unroll")                                                        \
        for (int ks = 0; ks < 2; ++ks) {                                         \
            const int cx = (((ks * 4 + quad) ^ (l15 & 7)) * 8);                  \
            short8 af[4], bfr[4];                                                \
            _Pragma("unroll")                                                    \
            for (int i = 0; i < 4; ++i) {                                        \
                af[i]  = *(const short8*)(&At[(wrow + i * 16 + l15) * 64 + cx]); \
                bfr[i] = *(const short8*)(&Bt[(wcol + i * 16 + l15) * 64 + cx]); \
            }                                                                    \
            _Pragma("unroll")                                                    \
            for (int mt = 0; mt < 4; ++mt)                                       \
                _Pragma("unroll")                                                \
                for (int nt = 0; nt < 4; ++nt)                                   \
                    acc[mt][nt] = mfma16(af[mt], bfr[nt], acc[mt][nt]);          \
        }                                                                        \
    }

// ---------------- fused QKV GEMM, mode = blockIdx.y ------------------------
// mode 0: Q = xq*Wq (+bq, *HD^-0.5*log2e, RoPE) -> bf16 (B,H,N,HD)
// mode 1: K = xkv*Wk (+bk, RoPE)               -> bf16 (B,H,N,HD)
// mode 2: V^T = Wvt*xkv^T (+bv per feat)       -> bf16 (H,HD,B,N)
__launch_bounds__(256, 4)
__global__ void qkv_gemm(const ushortT* __restrict__ xq, const ushortT* __restrict__ xkv,
                         const ushortT* __restrict__ Wqt, const ushortT* __restrict__ Wkt,
                         const ushortT* __restrict__ Wvt,
                         const float* __restrict__ bq, const float* __restrict__ bk,
                         const float* __restrict__ bv, const float* __restrict__ pe,
                         ushortT* __restrict__ q_ws, ushortT* __restrict__ k_ws,
                         ushortT* __restrict__ v_ws) {
    __shared__ ushortT At[128 * 64];
    __shared__ ushortT Bt[128 * 64];
    const int mode = blockIdx.y;
    const ushortT *A, *Bm; const float* bias; ushortT* outb;
    int bx, by;
    if (mode == 0)      { A = xq;  Bm = Wqt; bias = bq; outb = q_ws; bx = blockIdx.x & 7;  by = blockIdx.x >> 3; }
    else if (mode == 1) { A = xkv; Bm = Wkt; bias = bk; outb = k_ws; bx = blockIdx.x & 7;  by = blockIdx.x >> 3; }
    else                { A = Wvt; Bm = xkv; bias = bv; outb = v_ws; bx = blockIdx.x & 63; by = blockIdx.x >> 6; }
    const int mBase = by * 128, nBase = bx * 128;

    GEMM_CORE(A, Bm)

#pragma unroll
    for (int mt = 0; mt < 4; ++mt) {
#pragma unroll
        for (int nt = 0; nt < 4; ++nt) {
            const int col = nBase + wcol + nt * 16 + l15;
            const int row0 = mBase + wrow + mt * 16 + quad * 4;
            if (mode == 2) {
#pragma unroll
                for (int r = 0; r < 4; ++r) {
                    const int f = row0 + r;  // feature = h*64+hd
                    float v = acc[mt][nt][r] + bias[f];
                    const int h = f >> 6, hd = f & 63;
                    const int b = col >> 11, n = col & 2047;
                    uintT u = f2bf(v);
                    uintT pu = (uintT)__shfl_xor((int)u, 1);
                    if (!(l15 & 1)) {
                        size_t idx = ((size_t)((h * 64 + hd) * 4 + b) << 11) + n;
                        *(uintT*)(&outb[idx]) = u | (pu << 16);
                    }
                }
            } else {  // Q / K with RoPE; Q additionally scaled by HD^-0.5 * log2(e)
                const float bb = bias[col];
                const int h = col >> 6, hd = col & 63;
                const bool dorope = (hd < 32);
#pragma unroll
                for (int r = 0; r < 4; ++r) {
                    const int row = row0 + r;
                    const int b = row >> 11, n = row & 2047;
                    float v = acc[mt][nt][r] + bb;
                    if (mode == 0) v *= 0.180336880111f;  // 0.125 * log2(e)
                    if (dorope) {
                        float part = __shfl_xor(v, 1);
                        float p = pe[n * 32 + hd];
                        float cs = __cosf(p), sn = __sinf(p);
                        v = v * cs + ((hd & 1) ? part : -part) * sn;
                    }
                    uintT u = f2bf(v);
                    uintT pu = (uintT)__shfl_xor((int)u, 1);
                    if (!(l15 & 1)) {
                        size_t idx = (((size_t)(b * 16 + h) * 2048 + n) << 6) + hd;
                        *(uintT*)(&outb[idx]) = u | (pu << 16);
                    }
                }
            }
        }
    }
}

// ---------------- O projection (A = attn out bf16, out fp32) --------------
__launch_bounds__(256, 4)
__global__ void o_gemm(const ushortT* __restrict__ A, const ushortT* __restrict__ Bm,
                       const float* __restrict__ bias, float* __restrict__ outf) {
    __shared__ ushortT At[128 * 64];
    __shared__ ushortT Bt[128 * 64];
    const int mBase = blockIdx.y * 128, nBase = blockIdx.x * 128;

    GEMM_CORE(A, Bm)

#pragma unroll
    for (int mt = 0; mt < 4; ++mt)
#pragma unroll
        for (int nt = 0; nt < 4; ++nt) {
            const int col = nBase + wcol + nt * 16 + l15;
            const int row0 = mBase + wrow + mt * 16 + quad * 4;
            const float bb = bias[col];
#pragma unroll
            for (int r = 0; r < 4; ++r)
                outf[(size_t)(row0 + r) * 1024 + col] = acc[mt][nt][r] + bb;
        }
}

// ---------------- flash attention, causal, fixed-shift softmax ------------
// Q,K: (BH=64, N=2048, HD=64) bf16 (Q pre-scaled by HD^-0.5*log2e).
// Vt: (H,HD,B,N) bf16.  O: (B,N,H,HD) bf16.
// 256-query blocks: 4 waves x 64 queries -> K/V LDS reads amortized over 2x
// more queries, and half the tile-steps (barrier drains) vs 128q blocks.
// LDS 48KB (K 16 + V 16 + P 4x4KB) -> 3 blocks/CU.
__launch_bounds__(256, 3)
__global__ void attn_fwd(const ushortT* __restrict__ Q, const ushortT* __restrict__ K,
                         const ushortT* __restrict__ Vt, ushortT* __restrict__ O) {
    __shared__ ushortT Kl[128 * 64];      // [key][hd], chunk c holds global c^(key&7)
    __shared__ ushortT Vl[64 * 128];      // [hd][key], chunk c holds global c^(hd&7)
    __shared__ ushortT Pl[4 * 64 * 32];   // per-wave 64q x 32k, chunk c^( (q>>2)&3 )
    const int t = threadIdx.x;
    const int wave = t >> 6, lane = t & 63, quad = lane >> 4, l15 = lane & 15;
    // complement-paired qtile map: co-resident blocks (by, by^32) get q and 7-q
    const int qt8 = (blockIdx.x + blockIdx.y) & 7;
    const int qtile = (blockIdx.y & 32) ? 7 - qt8 : qt8;
    const int bh = blockIdx.y, b = bh >> 4, h = bh & 15;
    const int qbase = qtile * 256;

    // staging constants (lane-linear LDS dests, XOR folded into global addr)
    const int kkey_l = wave * 8 + (lane >> 3);
    const int kcg = ((lane & 7) ^ (lane >> 3)) * 8;
    const int hd_l = wave * 4 + (lane >> 4);
    const int vcg = ((lane & 15) ^ (hd_l & 7)) * 8;
    const ushortT* kptr = K + (size_t)bh * 2048 * 64 + (size_t)kkey_l * 64 + kcg;
    const ushortT* vptr = Vt + ((size_t)((h * 64 + hd_l) * 4 + b)) * 2048 + vcg;
    const unsigned ldst = wave * 512 + lane * 8;

    // Q fragments: 64 rows per wave
    short8 qf[4][2];
#pragma unroll
    for (int fm = 0; fm < 4; ++fm)
#pragma unroll
        for (int ks = 0; ks < 2; ++ks) {
            int row = qbase + wave * 64 + fm * 16 + l15;
            qf[fm][ks] = *(const short8*)(Q + ((size_t)bh * 2048 + row) * 64 + ks * 32 + quad * 8);
        }

    floatx4 oacc[4][4] = {};
    floatx4 lacc[4] = {};
    const unsigned wbase = wave * 2048;
    // P store base (swizzle s=(q>>2)&3 -> equals `quad` for this lane's rows)
    // addr(fm,f2,r) = wbase + (fm*16+quad*4+r)*32 + (((f2*2+(l15>>3))^quad)*8) + (l15&7)
    const unsigned psb0 = wbase + quad * 4 * 32 + ((((l15 >> 3)) ^ quad) * 8) + (l15 & 7);
    const unsigned psb1 = wbase + quad * 4 * 32 + (((2 + (l15 >> 3)) ^ quad) * 8) + (l15 & 7);
    // P read base: q = fm*16 + l15, chunk = quad ^ ((l15>>2)&3)
    const unsigned prb = wbase + l15 * 32 + ((quad ^ ((l15 >> 2) & 3)) * 8);

    short8 ones;
#pragma unroll
    for (int i = 0; i < 8; ++i) ones[i] = (short)0x3F80;  // bf16 1.0

    const int ntiles = 2 * qtile + 2;
    for (int jt = 0; jt < ntiles; ++jt) {
        const int jb = jt * 128;
        __syncthreads();
#pragma unroll
        for (int it = 0; it < 4; ++it)
            gl_lds16(kptr + (size_t)jt * 8192 + it * 2048, &Kl[it * 2048 + ldst]);
#pragma unroll
        for (int it = 0; it < 4; ++it)
            gl_lds16(vptr + (size_t)jt * 128 + (size_t)it * 131072, &Vl[it * 2048 + ldst]);
        __syncthreads();

        const bool diagzone = (jt >= 2 * qtile);
        // waves whose rows are entirely above this key tile skip compute
        if (wave * 64 + 63 + qbase >= jb) {
#pragma unroll
            for (int ks2 = 0; ks2 < 4; ++ks2) {
                // --- S (64q x 32k) -> exp2 -> P in LDS ---
#pragma unroll
                for (int f2 = 0; f2 < 2; ++f2) {
                    const int kk = (ks2 * 2 + f2) * 16 + l15;  // key within tile
                    floatx4 sv[4] = {};
#pragma unroll
                    for (int ks = 0; ks < 2; ++ks) {
                        const int c = ks * 4 + quad;
                        short8 kf = *(const short8*)(&Kl[kk * 64 + ((c ^ (l15 & 7)) * 8)]);
#pragma unroll
                        for (int fm = 0; fm < 4; ++fm)
                            sv[fm] = mfma16(qf[fm][ks], kf, sv[fm]);
                    }
                    const unsigned ps = f2 ? psb1 : psb0;
#pragma unroll
                    for (int fm = 0; fm < 4; ++fm) {
                        const int qg = qbase + wave * 64 + fm * 16 + quad * 4;  // row of r=0
#pragma unroll
                        for (int r = 0; r < 4; ++r) {
                            float e = (diagzone && (jb + kk > qg + r)) ? 0.f
                                      : __builtin_amdgcn_exp2f(sv[fm][r]);
                            Pl[ps + fm * 512 + r * 32] = f2bf_tr(e);
                        }
                    }
                }
                // --- O += P * V; row sums via ones-fragment ---
                short8 pf[4];
#pragma unroll
                for (int fm = 0; fm < 4; ++fm) {
                    pf[fm] = *(const short8*)(&Pl[prb + fm * 512]);
                    lacc[fm] = mfma16(pf[fm], ones, lacc[fm]);
                }
#pragma unroll
                for (int fv = 0; fv < 4; ++fv) {
                    const int hd = fv * 16 + l15;
                    const int c = ks2 * 4 + quad;
                    short8 vf = *(const short8*)(&Vl[hd * 128 + ((c ^ (l15 & 7)) * 8)]);
#pragma unroll
                    for (int fm = 0; fm < 4; ++fm)
                        oacc[fm][fv] = mfma16(pf[fm], vf, oacc[fm][fv]);
                }
            }
        }
    }
    // write O (B,N,H,HD); every lane holds full row sums in lacc
#pragma unroll
    for (int fm = 0; fm < 4; ++fm) {
        float lr[4];
#pragma unroll
        for (int r = 0; r < 4; ++r) lr[r] = __builtin_amdgcn_rcpf(lacc[fm][r]);
#pragma unroll
        for (int fv = 0; fv < 4; ++fv)
#pragma unroll
            for (int r = 0; r < 4; ++r) {
                int qrow = qbase + wave * 64 + fm * 16 + quad * 4 + r;
                float v = oacc[fm][fv][r] * lr[r];
                int hd = fv * 16 + l15;
                uintT u = f2bf(v);
                uintT pu = (uintT)__shfl_xor((int)u, 1);
                if (!(l15 & 1)) {
                    size_t idx = (((size_t)(b * 2048 + qrow) * 16 + h) << 6) + hd;
                    *(uintT*)(&O[idx]) = u | (pu << 16);
                }
            }
    }
}

extern "C" void kernel_launch(void* const* d_in, const int* in_sizes, int n_in,
                              void* d_out, int out_size, void* d_ws, size_t ws_size,
                              hipStream_t stream) {
    const float* x_q  = (const float*)d_in[0];
    const float* x_kv = (const float*)d_in[1];
    const float* pe   = (const float*)d_in[2];
    const float* Wq   = (const float*)d_in[3];
    const float* bq   = (const float*)d_in[4];
    const float* Wk   = (const float*)d_in[5];
    const float* bk   = (const float*)d_in[6];
    const float* Wv   = (const float*)d_in[7];
    const float* bv   = (const float*)d_in[8];
    const float* Wo   = (const float*)d_in[9];
    const float* bo   = (const float*)d_in[10];
    float* out = (float*)d_out;

    char* ws = (char*)d_ws;
    const size_t MB = 1024 * 1024;
    ushortT* xq_bf  = (ushortT*)(ws + 0);
    ushortT* o_ws   = (ushortT*)(ws + 0);   // aliased: xq dead before attn
    ushortT* xkv_bf = (ushortT*)(ws + 16 * MB);
    ushortT* Wqt    = (ushortT*)(ws + 32 * MB);
    ushortT* Wkt    = (ushortT*)(ws + 34 * MB);
    ushortT* Wvt    = (ushortT*)(ws + 36 * MB);
    ushortT* Wot    = (ushortT*)(ws + 38 * MB);
    ushortT* q_ws   = (ushortT*)(ws + 40 * MB);
    ushortT* k_ws   = (ushortT*)(ws + 56 * MB);
    ushortT* v_ws   = (ushortT*)(ws + 72 * MB);

    cvt_bf16_2<<<16384, 256, 0, stream>>>(x_q, x_kv, xq_bf, xkv_bf);
    wtrans<<<dim3(16, 16, 4), 256, 0, stream>>>(Wq, Wk, Wv, Wo, Wqt, Wkt, Wvt, Wot);
    qkv_gemm<<<dim3(512, 3), 256, 0, stream>>>(xq_bf, xkv_bf, Wqt, Wkt, Wvt,
                                               bq, bk, bv, pe, q_ws, k_ws, v_ws);
    attn_fwd<<<dim3(8, 64), 256, 0, stream>>>(q_ws, k_ws, v_ws, o_ws);
    o_gemm<<<dim3(8, 64), 256, 0, stream>>>(o_ws, Wot, bo, out);
}

// Round 5
// 338.698 us; speedup vs baseline: 1.3141x; 1.3141x over previous
//
#include <hip/hip_runtime.h>
#include <cstdint>

// Problem constants: B=4, N=2048, D=1024, H=16, HD=64, RD=32, K=1024
typedef unsigned short ushortT;
typedef unsigned int uintT;
typedef __attribute__((ext_vector_type(8))) short short8;
typedef __attribute__((ext_vector_type(8))) __bf16 bf16x8;
typedef __attribute__((ext_vector_type(4))) float floatx4;
typedef __attribute__((ext_vector_type(4))) unsigned int u32x4;
typedef __attribute__((ext_vector_type(2))) unsigned int u32x2;

__device__ __forceinline__ void gl_lds16(const void* g, void* l) {
    auto gp = reinterpret_cast<const __attribute__((address_space(1))) unsigned int*>(
        reinterpret_cast<uintptr_t>(g));
    auto lp = reinterpret_cast<__attribute__((address_space(3))) unsigned int*>(
        reinterpret_cast<uintptr_t>(l));
    __builtin_amdgcn_global_load_lds(gp, lp, 16, 0, 0);
}

__device__ __forceinline__ ushortT f2bf(float f) {  // RNE
    unsigned int u = __float_as_uint(f);
    u = (u + 0x7FFFu + ((u >> 16) & 1u)) >> 16;
    return (ushortT)u;
}
__device__ __forceinline__ ushortT f2bf_tr(float f) {  // truncate (P matrix only)
    return (ushortT)(__float_as_uint(f) >> 16);
}

__device__ __forceinline__ floatx4 mfma16(short8 a, short8 b, floatx4 c) {
    return __builtin_amdgcn_mfma_f32_16x16x32_bf16(
        __builtin_bit_cast(bf16x8, a), __builtin_bit_cast(bf16x8, b), c, 0, 0, 0);
}

// ---------------- fp32 -> bf16 for x_q and x_kv (grid 16384) --------------
__global__ void cvt_bf16_2(const float* __restrict__ a, const float* __restrict__ b,
                           ushortT* __restrict__ oa, ushortT* __restrict__ ob) {
    int bid = blockIdx.x;
    const float* in; ushortT* out;
    if (bid < 8192) { in = a; out = oa; } else { in = b; out = ob; bid -= 8192; }
    size_t i = ((size_t)bid * 256 + threadIdx.x) * 4;
    floatx4 v = *(const floatx4*)(in + i);
    u32x2 p;
    p[0] = (uintT)f2bf(v[0]) | ((uintT)f2bf(v[1]) << 16);
    p[1] = (uintT)f2bf(v[2]) | ((uintT)f2bf(v[3]) << 16);
    *(u32x2*)(out + i) = p;
}

// ---------------- W (1024x1024 fp32 [k][n]) -> Wt (bf16 [n][k]) -----------
__global__ void wtrans(const float* __restrict__ Wq, const float* __restrict__ Wk,
                       const float* __restrict__ Wv, const float* __restrict__ Wo,
                       ushortT* __restrict__ Tq, ushortT* __restrict__ Tk,
                       ushortT* __restrict__ Tv, ushortT* __restrict__ To) {
    __shared__ float T[64][65];
    const float* src; ushortT* dst;
    switch (blockIdx.z) {
        case 0: src = Wq; dst = Tq; break;
        case 1: src = Wk; dst = Tk; break;
        case 2: src = Wv; dst = Tv; break;
        default: src = Wo; dst = To; break;
    }
    const int t = threadIdx.x, lx = t & 63, ly0 = t >> 6;
    const int kt = blockIdx.y * 64, nt = blockIdx.x * 64;
#pragma unroll
    for (int i = 0; i < 16; ++i) {
        int ly = i * 4 + ly0;
        T[ly][lx] = src[(size_t)(kt + ly) * 1024 + nt + lx];
    }
    __syncthreads();
#pragma unroll
    for (int i = 0; i < 16; ++i) {
        int ly = i * 4 + ly0;
        dst[(size_t)(nt + ly) * 1024 + kt + lx] = f2bf(T[lx][ly]);
    }
}

// ======== shared GEMM core: 128x128 tile, BK=64, swizzled LDS =============
// LDS layout: X[row][64], 16B chunk c stores global chunk (c ^ (row&7)).
// Staged via gl_lds16 with the XOR folded into the GLOBAL address so the
// LDS destination stays lane-linear. Fragment reads are then 2-way = free.
#define GEMM_CORE(A_, B_)                                                        \
    const int t = threadIdx.x;                                                   \
    const int wave = t >> 6, lane = t & 63;                                      \
    const int quad = lane >> 4, l15 = lane & 15;                                 \
    const int wrow = (wave >> 1) * 64, wcol = (wave & 1) * 64;                   \
    floatx4 acc[4][4] = {};                                                      \
    const int srb = t >> 3;                                                      \
    const int schx = ((t & 7) ^ (srb & 7)) * 8;                                  \
    for (int kt = 0; kt < 16; ++kt) {                                            \
        const int k0 = kt * 64;                                                  \
        if (kt) __syncthreads();                                                 \
        _Pragma("unroll")                                                        \
        for (int p = 0; p < 4; ++p) {                                            \
            int row = p * 32 + srb;                                              \
            gl_lds16(A_ + (size_t)(mBase + row) * 1024 + k0 + schx,              \
                     &At[p * 2048 + t * 8]);                                     \
            gl_lds16(B_ + (size_t)(nBase + row) * 1024 + k0 + schx,              \
                     &Bt[p * 2048 + t * 8]);                                     \
        }                                                                        \
        __syncthreads();                                                         \
        _Pragma("unroll")                                                        \
        for (int ks = 0; ks < 2; ++ks) {                                         \
            const int cx = (((ks * 4 + quad) ^ (l15 & 7)) * 8);                  \
            short8 af[4], bfr[4];                                                \
            _Pragma("unroll")                                                    \
            for (int i = 0; i < 4; ++i) {                                        \
                af[i]  = *(const short8*)(&At[(wrow + i * 16 + l15) * 64 + cx]); \
                bfr[i] = *(const short8*)(&Bt[(wcol + i * 16 + l15) * 64 + cx]); \
            }                                                                    \
            _Pragma("unroll")                                                    \
            for (int mt = 0; mt < 4; ++mt)                                       \
                _Pragma("unroll")                                                \
                for (int nt = 0; nt < 4; ++nt)                                   \
                    acc[mt][nt] = mfma16(af[mt], bfr[nt], acc[mt][nt]);          \
        }                                                                        \
    }

// ---------------- fused QKV GEMM, mode = blockIdx.y ------------------------
// mode 0: Q = xq*Wq (+bq, *HD^-0.5*log2e, RoPE) -> bf16 (B,H,N,HD)
// mode 1: K = xkv*Wk (+bk, RoPE)               -> bf16 (B,H,N,HD)
// mode 2: V^T = Wvt*xkv^T (+bv per feat)       -> bf16 (H,HD,B,N)
__launch_bounds__(256, 4)
__global__ void qkv_gemm(const ushortT* __restrict__ xq, const ushortT* __restrict__ xkv,
                         const ushortT* __restrict__ Wqt, const ushortT* __restrict__ Wkt,
                         const ushortT* __restrict__ Wvt,
                         const float* __restrict__ bq, const float* __restrict__ bk,
                         const float* __restrict__ bv, const float* __restrict__ pe,
                         ushortT* __restrict__ q_ws, ushortT* __restrict__ k_ws,
                         ushortT* __restrict__ v_ws) {
    __shared__ ushortT At[128 * 64];
    __shared__ ushortT Bt[128 * 64];
    const int mode = blockIdx.y;
    const ushortT *A, *Bm; const float* bias; ushortT* outb;
    int bx, by;
    if (mode == 0)      { A = xq;  Bm = Wqt; bias = bq; outb = q_ws; bx = blockIdx.x & 7;  by = blockIdx.x >> 3; }
    else if (mode == 1) { A = xkv; Bm = Wkt; bias = bk; outb = k_ws; bx = blockIdx.x & 7;  by = blockIdx.x >> 3; }
    else                { A = Wvt; Bm = xkv; bias = bv; outb = v_ws; bx = blockIdx.x & 63; by = blockIdx.x >> 6; }
    const int mBase = by * 128, nBase = bx * 128;

    GEMM_CORE(A, Bm)

#pragma unroll
    for (int mt = 0; mt < 4; ++mt) {
#pragma unroll
        for (int nt = 0; nt < 4; ++nt) {
            const int col = nBase + wcol + nt * 16 + l15;
            const int row0 = mBase + wrow + mt * 16 + quad * 4;
            if (mode == 2) {
#pragma unroll
                for (int r = 0; r < 4; ++r) {
                    const int f = row0 + r;  // feature = h*64+hd
                    float v = acc[mt][nt][r] + bias[f];
                    const int h = f >> 6, hd = f & 63;
                    const int b = col >> 11, n = col & 2047;
                    uintT u = f2bf(v);
                    uintT pu = (uintT)__shfl_xor((int)u, 1);
                    if (!(l15 & 1)) {
                        size_t idx = ((size_t)((h * 64 + hd) * 4 + b) << 11) + n;
                        *(uintT*)(&outb[idx]) = u | (pu << 16);
                    }
                }
            } else {  // Q / K with RoPE; Q additionally scaled by HD^-0.5 * log2(e)
                const float bb = bias[col];
                const int h = col >> 6, hd = col & 63;
                const bool dorope = (hd < 32);
#pragma unroll
                for (int r = 0; r < 4; ++r) {
                    const int row = row0 + r;
                    const int b = row >> 11, n = row & 2047;
                    float v = acc[mt][nt][r] + bb;
                    if (mode == 0) v *= 0.180336880111f;  // 0.125 * log2(e)
                    if (dorope) {
                        float part = __shfl_xor(v, 1);
                        float p = pe[n * 32 + hd];
                        float cs = __cosf(p), sn = __sinf(p);
                        v = v * cs + ((hd & 1) ? part : -part) * sn;
                    }
                    uintT u = f2bf(v);
                    uintT pu = (uintT)__shfl_xor((int)u, 1);
                    if (!(l15 & 1)) {
                        size_t idx = (((size_t)(b * 16 + h) * 2048 + n) << 6) + hd;
                        *(uintT*)(&outb[idx]) = u | (pu << 16);
                    }
                }
            }
        }
    }
}

// ---------------- O projection (A = attn out bf16, out fp32) --------------
__launch_bounds__(256, 4)
__global__ void o_gemm(const ushortT* __restrict__ A, const ushortT* __restrict__ Bm,
                       const float* __restrict__ bias, float* __restrict__ outf) {
    __shared__ ushortT At[128 * 64];
    __shared__ ushortT Bt[128 * 64];
    const int mBase = blockIdx.y * 128, nBase = blockIdx.x * 128;

    GEMM_CORE(A, Bm)

#pragma unroll
    for (int mt = 0; mt < 4; ++mt)
#pragma unroll
        for (int nt = 0; nt < 4; ++nt) {
            const int col = nBase + wcol + nt * 16 + l15;
            const int row0 = mBase + wrow + mt * 16 + quad * 4;
            const float bb = bias[col];
#pragma unroll
            for (int r = 0; r < 4; ++r)
                outf[(size_t)(row0 + r) * 1024 + col] = acc[mt][nt][r] + bb;
        }
}

// ---------------- flash attention, causal, fixed-shift softmax ------------
// Q,K: (BH=64, N=2048, HD=64) bf16 (Q pre-scaled by HD^-0.5*log2e).
// Vt: (H,HD,B,N) bf16.  O: (B,N,H,HD) bf16.
// 256-query blocks: 4 waves x 64 queries.
// __launch_bounds__(256,2): ~180 unified VGPRs/lane needed; the (256,3) cap
// of 168 caused scratch spills (R4: WRITE_SIZE 280 MB, MfmaUtil 8%).
// P tile row stride = 36 elements (not 32): bank = (18q + x/2) mod 32, so the
// four quads' simultaneous stores (rows quad*4+r) land on disjoint 8-bank
// sets -> conflict-free (stride 32 gave 8-way: 16q mod 32 is quad-invariant).
// LDS 16K (K) + 16K (V) + 18K (P) = 50 KB.
__launch_bounds__(256, 2)
__global__ void attn_fwd(const ushortT* __restrict__ Q, const ushortT* __restrict__ K,
                         const ushortT* __restrict__ Vt, ushortT* __restrict__ O) {
    __shared__ ushortT Kl[128 * 64];      // [key][hd], chunk c holds global c^(key&7)
    __shared__ ushortT Vl[64 * 128];      // [hd][key], chunk c holds global c^(hd&7)
    __shared__ ushortT Pl[4 * 64 * 36];   // per-wave 64q x 32k, row stride 36
    const int t = threadIdx.x;
    const int wave = t >> 6, lane = t & 63, quad = lane >> 4, l15 = lane & 15;
    // complement-paired qtile map: blocks 256 apart get qtiles q and 7-q
    const int qt8 = (blockIdx.x + blockIdx.y) & 7;
    const int qtile = (blockIdx.y & 32) ? 7 - qt8 : qt8;
    const int bh = blockIdx.y, b = bh >> 4, h = bh & 15;
    const int qbase = qtile * 256;

    // staging constants (lane-linear LDS dests, XOR folded into global addr)
    const int kkey_l = wave * 8 + (lane >> 3);
    const int kcg = ((lane & 7) ^ (lane >> 3)) * 8;
    const int hd_l = wave * 4 + (lane >> 4);
    const int vcg = ((lane & 15) ^ (hd_l & 7)) * 8;
    const ushortT* kptr = K + (size_t)bh * 2048 * 64 + (size_t)kkey_l * 64 + kcg;
    const ushortT* vptr = Vt + ((size_t)((h * 64 + hd_l) * 4 + b)) * 2048 + vcg;
    const unsigned ldst = wave * 512 + lane * 8;

    // Q fragments: 64 rows per wave
    short8 qf[4][2];
#pragma unroll
    for (int fm = 0; fm < 4; ++fm)
#pragma unroll
        for (int ks = 0; ks < 2; ++ks) {
            int row = qbase + wave * 64 + fm * 16 + l15;
            qf[fm][ks] = *(const short8*)(Q + ((size_t)bh * 2048 + row) * 64 + ks * 32 + quad * 8);
        }

    floatx4 oacc[4][4] = {};
    floatx4 lacc[4] = {};
    const unsigned wbase = wave * 2304;  // 64 rows * 36
    // P store base: addr(fm,f2,r) = wbase + (fm*16+quad*4+r)*36
    //                + (((f2*2+(l15>>3)) ^ quad)*8) + (l15&7)
    const unsigned psb0 = wbase + quad * 4 * 36 + ((((l15 >> 3)) ^ quad) * 8) + (l15 & 7);
    const unsigned psb1 = wbase + quad * 4 * 36 + (((2 + (l15 >> 3)) ^ quad) * 8) + (l15 & 7);
    // P read base: q = fm*16 + l15, chunk = quad ^ ((l15>>2)&3)
    const unsigned prb = wbase + l15 * 36 + ((quad ^ ((l15 >> 2) & 3)) * 8);

    short8 ones;
#pragma unroll
    for (int i = 0; i < 8; ++i) ones[i] = (short)0x3F80;  // bf16 1.0

    const int ntiles = 2 * qtile + 2;
    for (int jt = 0; jt < ntiles; ++jt) {
        const int jb = jt * 128;
        __syncthreads();
#pragma unroll
        for (int it = 0; it < 4; ++it)
            gl_lds16(kptr + (size_t)jt * 8192 + it * 2048, &Kl[it * 2048 + ldst]);
#pragma unroll
        for (int it = 0; it < 4; ++it)
            gl_lds16(vptr + (size_t)jt * 128 + (size_t)it * 131072, &Vl[it * 2048 + ldst]);
        __syncthreads();

        const bool diagzone = (jt >= 2 * qtile);
        // waves whose rows are entirely above this key tile skip compute
        if (wave * 64 + 63 + qbase >= jb) {
#pragma unroll
            for (int ks2 = 0; ks2 < 4; ++ks2) {
                // --- S (64q x 32k) -> exp2 -> P in LDS ---
#pragma unroll
                for (int f2 = 0; f2 < 2; ++f2) {
                    const int kk = (ks2 * 2 + f2) * 16 + l15;  // key within tile
                    floatx4 sv[4] = {};
#pragma unroll
                    for (int ks = 0; ks < 2; ++ks) {
                        const int c = ks * 4 + quad;
                        short8 kf = *(const short8*)(&Kl[kk * 64 + ((c ^ (l15 & 7)) * 8)]);
#pragma unroll
                        for (int fm = 0; fm < 4; ++fm)
                            sv[fm] = mfma16(qf[fm][ks], kf, sv[fm]);
                    }
                    const unsigned ps = f2 ? psb1 : psb0;
#pragma unroll
                    for (int fm = 0; fm < 4; ++fm) {
                        const int qg = qbase + wave * 64 + fm * 16 + quad * 4;  // row of r=0
#pragma unroll
                        for (int r = 0; r < 4; ++r) {
                            float e = (diagzone && (jb + kk > qg + r)) ? 0.f
                                      : __builtin_amdgcn_exp2f(sv[fm][r]);
                            Pl[ps + fm * 576 + r * 36] = f2bf_tr(e);
                        }
                    }
                }
                // --- O += P * V; row sums via ones-fragment ---
                short8 pf[4];
#pragma unroll
                for (int fm = 0; fm < 4; ++fm) {
                    pf[fm] = *(const short8*)(&Pl[prb + fm * 576]);
                    lacc[fm] = mfma16(pf[fm], ones, lacc[fm]);
                }
#pragma unroll
                for (int fv = 0; fv < 4; ++fv) {
                    const int hd = fv * 16 + l15;
                    const int c = ks2 * 4 + quad;
                    short8 vf = *(const short8*)(&Vl[hd * 128 + ((c ^ (l15 & 7)) * 8)]);
#pragma unroll
                    for (int fm = 0; fm < 4; ++fm)
                        oacc[fm][fv] = mfma16(pf[fm], vf, oacc[fm][fv]);
                }
            }
        }
    }
    // write O (B,N,H,HD); every lane holds full row sums in lacc
#pragma unroll
    for (int fm = 0; fm < 4; ++fm) {
        float lr[4];
#pragma unroll
        for (int r = 0; r < 4; ++r) lr[r] = __builtin_amdgcn_rcpf(lacc[fm][r]);
#pragma unroll
        for (int fv = 0; fv < 4; ++fv)
#pragma unroll
            for (int r = 0; r < 4; ++r) {
                int qrow = qbase + wave * 64 + fm * 16 + quad * 4 + r;
                float v = oacc[fm][fv][r] * lr[r];
                int hd = fv * 16 + l15;
                uintT u = f2bf(v);
                uintT pu = (uintT)__shfl_xor((int)u, 1);
                if (!(l15 & 1)) {
                    size_t idx = (((size_t)(b * 2048 + qrow) * 16 + h) << 6) + hd;
                    *(uintT*)(&O[idx]) = u | (pu << 16);
                }
            }
    }
}

extern "C" void kernel_launch(void* const* d_in, const int* in_sizes, int n_in,
                              void* d_out, int out_size, void* d_ws, size_t ws_size,
                              hipStream_t stream) {
    const float* x_q  = (const float*)d_in[0];
    const float* x_kv = (const float*)d_in[1];
    const float* pe   = (const float*)d_in[2];
    const float* Wq   = (const float*)d_in[3];
    const float* bq   = (const float*)d_in[4];
    const float* Wk   = (const float*)d_in[5];
    const float* bk   = (const float*)d_in[6];
    const float* Wv   = (const float*)d_in[7];
    const float* bv   = (const float*)d_in[8];
    const float* Wo   = (const float*)d_in[9];
    const float* bo   = (const float*)d_in[10];
    float* out = (float*)d_out;

    char* ws = (char*)d_ws;
    const size_t MB = 1024 * 1024;
    ushortT* xq_bf  = (ushortT*)(ws + 0);
    ushortT* o_ws   = (ushortT*)(ws + 0);   // aliased: xq dead before attn
    ushortT* xkv_bf = (ushortT*)(ws + 16 * MB);
    ushortT* Wqt    = (ushortT*)(ws + 32 * MB);
    ushortT* Wkt    = (ushortT*)(ws + 34 * MB);
    ushortT* Wvt    = (ushortT*)(ws + 36 * MB);
    ushortT* Wot    = (ushortT*)(ws + 38 * MB);
    ushortT* q_ws   = (ushortT*)(ws + 40 * MB);
    ushortT* k_ws   = (ushortT*)(ws + 56 * MB);
    ushortT* v_ws   = (ushortT*)(ws + 72 * MB);

    cvt_bf16_2<<<16384, 256, 0, stream>>>(x_q, x_kv, xq_bf, xkv_bf);
    wtrans<<<dim3(16, 16, 4), 256, 0, stream>>>(Wq, Wk, Wv, Wo, Wqt, Wkt, Wvt, Wot);
    qkv_gemm<<<dim3(512, 3), 256, 0, stream>>>(xq_bf, xkv_bf, Wqt, Wkt, Wvt,
                                               bq, bk, bv, pe, q_ws, k_ws, v_ws);
    attn_fwd<<<dim3(8, 64), 256, 0, stream>>>(q_ws, k_ws, v_ws, o_ws);
    o_gemm<<<dim3(8, 64), 256, 0, stream>>>(o_ws, Wot, bo, out);
}

// Round 6
// 317.527 us; speedup vs baseline: 1.4017x; 1.0667x over previous
//
#include <hip/hip_runtime.h>
#include <cstdint>

// Problem constants: B=4, N=2048, D=1024, H=16, HD=64, RD=32, K=1024
typedef unsigned short ushortT;
typedef unsigned int uintT;
typedef __attribute__((ext_vector_type(8))) short short8;
typedef __attribute__((ext_vector_type(8))) __bf16 bf16x8;
typedef __attribute__((ext_vector_type(4))) float floatx4;
typedef __attribute__((ext_vector_type(4))) unsigned int u32x4;
typedef __attribute__((ext_vector_type(2))) unsigned int u32x2;

__device__ __forceinline__ void gl_lds16(const void* g, void* l) {
    auto gp = reinterpret_cast<const __attribute__((address_space(1))) unsigned int*>(
        reinterpret_cast<uintptr_t>(g));
    auto lp = reinterpret_cast<__attribute__((address_space(3))) unsigned int*>(
        reinterpret_cast<uintptr_t>(l));
    __builtin_amdgcn_global_load_lds(gp, lp, 16, 0, 0);
}

__device__ __forceinline__ ushortT f2bf(float f) {  // RNE
    unsigned int u = __float_as_uint(f);
    u = (u + 0x7FFFu + ((u >> 16) & 1u)) >> 16;
    return (ushortT)u;
}
__device__ __forceinline__ ushortT f2bf_tr(float f) {  // truncate (P matrix only)
    return (ushortT)(__float_as_uint(f) >> 16);
}

__device__ __forceinline__ floatx4 mfma16(short8 a, short8 b, floatx4 c) {
    return __builtin_amdgcn_mfma_f32_16x16x32_bf16(
        __builtin_bit_cast(bf16x8, a), __builtin_bit_cast(bf16x8, b), c, 0, 0, 0);
}

// ---------------- fp32 -> bf16 for x_q and x_kv (grid 16384) --------------
__global__ void cvt_bf16_2(const float* __restrict__ a, const float* __restrict__ b,
                           ushortT* __restrict__ oa, ushortT* __restrict__ ob) {
    int bid = blockIdx.x;
    const float* in; ushortT* out;
    if (bid < 8192) { in = a; out = oa; } else { in = b; out = ob; bid -= 8192; }
    size_t i = ((size_t)bid * 256 + threadIdx.x) * 4;
    floatx4 v = *(const floatx4*)(in + i);
    u32x2 p;
    p[0] = (uintT)f2bf(v[0]) | ((uintT)f2bf(v[1]) << 16);
    p[1] = (uintT)f2bf(v[2]) | ((uintT)f2bf(v[3]) << 16);
    *(u32x2*)(out + i) = p;
}

// ---------------- W (1024x1024 fp32 [k][n]) -> Wt (bf16 [n][k]) -----------
__global__ void wtrans(const float* __restrict__ Wq, const float* __restrict__ Wk,
                       const float* __restrict__ Wv, const float* __restrict__ Wo,
                       ushortT* __restrict__ Tq, ushortT* __restrict__ Tk,
                       ushortT* __restrict__ Tv, ushortT* __restrict__ To) {
    __shared__ float T[64][65];
    const float* src; ushortT* dst;
    switch (blockIdx.z) {
        case 0: src = Wq; dst = Tq; break;
        case 1: src = Wk; dst = Tk; break;
        case 2: src = Wv; dst = Tv; break;
        default: src = Wo; dst = To; break;
    }
    const int t = threadIdx.x, lx = t & 63, ly0 = t >> 6;
    const int kt = blockIdx.y * 64, nt = blockIdx.x * 64;
#pragma unroll
    for (int i = 0; i < 16; ++i) {
        int ly = i * 4 + ly0;
        T[ly][lx] = src[(size_t)(kt + ly) * 1024 + nt + lx];
    }
    __syncthreads();
#pragma unroll
    for (int i = 0; i < 16; ++i) {
        int ly = i * 4 + ly0;
        dst[(size_t)(nt + ly) * 1024 + kt + lx] = f2bf(T[lx][ly]);
    }
}

// ======== shared GEMM core: 128x128 tile, BK=64, swizzled LDS =============
#define GEMM_CORE(A_, B_)                                                        \
    const int t = threadIdx.x;                                                   \
    const int wave = t >> 6, lane = t & 63;                                      \
    const int quad = lane >> 4, l15 = lane & 15;                                 \
    const int wrow = (wave >> 1) * 64, wcol = (wave & 1) * 64;                   \
    floatx4 acc[4][4] = {};                                                      \
    const int srb = t >> 3;                                                      \
    const int schx = ((t & 7) ^ (srb & 7)) * 8;                                  \
    for (int kt = 0; kt < 16; ++kt) {                                            \
        const int k0 = kt * 64;                                                  \
        if (kt) __syncthreads();                                                 \
        _Pragma("unroll")                                                        \
        for (int p = 0; p < 4; ++p) {                                            \
            int row = p * 32 + srb;                                              \
            gl_lds16(A_ + (size_t)(mBase + row) * 1024 + k0 + schx,              \
                     &At[p * 2048 + t * 8]);                                     \
            gl_lds16(B_ + (size_t)(nBase + row) * 1024 + k0 + schx,              \
                     &Bt[p * 2048 + t * 8]);                                     \
        }                                                                        \
        __syncthreads();                                                         \
        _Pragma("unroll")                                                        \
        for (int ks = 0; ks < 2; ++ks) {                                         \
            const int cx = (((ks * 4 + quad) ^ (l15 & 7)) * 8);                  \
            short8 af[4], bfr[4];                                                \
            _Pragma("unroll")                                                    \
            for (int i = 0; i < 4; ++i) {                                        \
                af[i]  = *(const short8*)(&At[(wrow + i * 16 + l15) * 64 + cx]); \
                bfr[i] = *(const short8*)(&Bt[(wcol + i * 16 + l15) * 64 + cx]); \
            }                                                                    \
            _Pragma("unroll")                                                    \
            for (int mt = 0; mt < 4; ++mt)                                       \
                _Pragma("unroll")                                                \
                for (int nt = 0; nt < 4; ++nt)                                   \
                    acc[mt][nt] = mfma16(af[mt], bfr[nt], acc[mt][nt]);          \
        }                                                                        \
    }

// ---------------- fused QKV GEMM, mode = blockIdx.y ------------------------
__launch_bounds__(256, 4)
__global__ void qkv_gemm(const ushortT* __restrict__ xq, const ushortT* __restrict__ xkv,
                         const ushortT* __restrict__ Wqt, const ushortT* __restrict__ Wkt,
                         const ushortT* __restrict__ Wvt,
                         const float* __restrict__ bq, const float* __restrict__ bk,
                         const float* __restrict__ bv, const float* __restrict__ pe,
                         ushortT* __restrict__ q_ws, ushortT* __restrict__ k_ws,
                         ushortT* __restrict__ v_ws) {
    __shared__ ushortT At[128 * 64];
    __shared__ ushortT Bt[128 * 64];
    const int mode = blockIdx.y;
    const ushortT *A, *Bm; const float* bias; ushortT* outb;
    int bx, by;
    if (mode == 0)      { A = xq;  Bm = Wqt; bias = bq; outb = q_ws; bx = blockIdx.x & 7;  by = blockIdx.x >> 3; }
    else if (mode == 1) { A = xkv; Bm = Wkt; bias = bk; outb = k_ws; bx = blockIdx.x & 7;  by = blockIdx.x >> 3; }
    else                { A = Wvt; Bm = xkv; bias = bv; outb = v_ws; bx = blockIdx.x & 63; by = blockIdx.x >> 6; }
    const int mBase = by * 128, nBase = bx * 128;

    GEMM_CORE(A, Bm)

#pragma unroll
    for (int mt = 0; mt < 4; ++mt) {
#pragma unroll
        for (int nt = 0; nt < 4; ++nt) {
            const int col = nBase + wcol + nt * 16 + l15;
            const int row0 = mBase + wrow + mt * 16 + quad * 4;
            if (mode == 2) {
#pragma unroll
                for (int r = 0; r < 4; ++r) {
                    const int f = row0 + r;  // feature = h*64+hd
                    float v = acc[mt][nt][r] + bias[f];
                    const int h = f >> 6, hd = f & 63;
                    const int b = col >> 11, n = col & 2047;
                    uintT u = f2bf(v);
                    uintT pu = (uintT)__shfl_xor((int)u, 1);
                    if (!(l15 & 1)) {
                        size_t idx = ((size_t)((h * 64 + hd) * 4 + b) << 11) + n;
                        *(uintT*)(&outb[idx]) = u | (pu << 16);
                    }
                }
            } else {  // Q / K with RoPE; Q additionally scaled by HD^-0.5 * log2(e)
                const float bb = bias[col];
                const int h = col >> 6, hd = col & 63;
                const bool dorope = (hd < 32);
#pragma unroll
                for (int r = 0; r < 4; ++r) {
                    const int row = row0 + r;
                    const int b = row >> 11, n = row & 2047;
                    float v = acc[mt][nt][r] + bb;
                    if (mode == 0) v *= 0.180336880111f;  // 0.125 * log2(e)
                    if (dorope) {
                        float part = __shfl_xor(v, 1);
                        float p = pe[n * 32 + hd];
                        float cs = __cosf(p), sn = __sinf(p);
                        v = v * cs + ((hd & 1) ? part : -part) * sn;
                    }
                    uintT u = f2bf(v);
                    uintT pu = (uintT)__shfl_xor((int)u, 1);
                    if (!(l15 & 1)) {
                        size_t idx = (((size_t)(b * 16 + h) * 2048 + n) << 6) + hd;
                        *(uintT*)(&outb[idx]) = u | (pu << 16);
                    }
                }
            }
        }
    }
}

// ---------------- O projection (A = attn out bf16, out fp32) --------------
__launch_bounds__(256, 4)
__global__ void o_gemm(const ushortT* __restrict__ A, const ushortT* __restrict__ Bm,
                       const float* __restrict__ bias, float* __restrict__ outf) {
    __shared__ ushortT At[128 * 64];
    __shared__ ushortT Bt[128 * 64];
    const int mBase = blockIdx.y * 128, nBase = blockIdx.x * 128;

    GEMM_CORE(A, Bm)

#pragma unroll
    for (int mt = 0; mt < 4; ++mt)
#pragma unroll
        for (int nt = 0; nt < 4; ++nt) {
            const int col = nBase + wcol + nt * 16 + l15;
            const int row0 = mBase + wrow + mt * 16 + quad * 4;
            const float bb = bias[col];
#pragma unroll
            for (int r = 0; r < 4; ++r)
                outf[(size_t)(row0 + r) * 1024 + col] = acc[mt][nt][r] + bb;
        }
}

// ---------------- flash attention, causal, fixed-shift softmax ------------
// Q,K: (BH=64, N=2048, HD=64) bf16 (Q pre-scaled by HD^-0.5*log2e).
// Vt: (H,HD,B,N) bf16.  O: (B,N,H,HD) bf16.
// Uniform phase-paired 128q blocks: grid (8,64); block bx does qtiles
// {15-bx, bx} -> exactly 17 tile-steps each; all 512 blocks co-resident.
// K/V staging is register-prefetched: tile jt+1 loads global->VGPR while
// tile jt computes; ds_write at loop top. The barrier no longer drains
// in-flight HBM loads (R5: ~3000 stall cyc/tile on the vmcnt(0) drain).
// P buffer: plain [row][36] layout; store bank = 8*quad + 18r + l15/2 ->
// conflict-free; reads 2-way (free).  LDS 41 KB.
__launch_bounds__(256, 2)
__global__ void attn_fwd(const ushortT* __restrict__ Q, const ushortT* __restrict__ K,
                         const ushortT* __restrict__ Vt, ushortT* __restrict__ O) {
    __shared__ ushortT Kl[128 * 64];      // [key][hd], chunk c holds global c^(key&7)
    __shared__ ushortT Vl[64 * 128];      // [hd][key], chunk c holds global c^(hd&7)
    __shared__ ushortT Pl[4 * 32 * 36];   // per-wave 32q x 32k, plain, stride 36
    const int t = threadIdx.x;
    const int wave = t >> 6, lane = t & 63, quad = lane >> 4, l15 = lane & 15;
    const int bh = blockIdx.y, b = bh >> 4, h = bh & 15;

    // staging constants (lane-linear LDS dests, XOR folded into global addr)
    const int kkey_l = wave * 8 + (lane >> 3);
    const int kcg = ((lane & 7) ^ (lane >> 3)) * 8;
    const int hd_l = wave * 4 + (lane >> 4);
    const int vcg = ((lane & 15) ^ (hd_l & 7)) * 8;
    const ushortT* Kb = K + (size_t)bh * 131072 + (size_t)kkey_l * 64 + kcg;
    const ushortT* Vb = Vt + ((size_t)((h * 64 + hd_l) * 4 + b)) * 2048 + vcg;
    const unsigned ldst = wave * 512 + lane * 8;

    const unsigned wbase = wave * 1152;  // 32 rows * 36
    const unsigned psb = wbase + quad * 4 * 36 + l15;  // + fm*576 + r*36 + f2*16
    const unsigned prb = wbase + l15 * 36 + quad * 8;  // + fm*576

    short8 ones;
#pragma unroll
    for (int i = 0; i < 8; ++i) ones[i] = (short)0x3F80;  // bf16 1.0

    for (int phase = 0; phase < 2; ++phase) {
        const int qtile = phase ? (int)blockIdx.x : 15 - (int)blockIdx.x;
        const int qbase = qtile * 128;

        short8 qf[2][2];
#pragma unroll
        for (int fm = 0; fm < 2; ++fm)
#pragma unroll
            for (int ks = 0; ks < 2; ++ks) {
                int row = qbase + wave * 32 + fm * 16 + l15;
                qf[fm][ks] = *(const short8*)(Q + ((size_t)bh * 2048 + row) * 64 + ks * 32 + quad * 8);
            }

        floatx4 oacc[2][4] = {};
        floatx4 lacc[2] = {};
        u32x4 kp[4], vp[4];
#pragma unroll
        for (int it = 0; it < 4; ++it) {  // prefetch tile 0
            kp[it] = *(const u32x4*)(Kb + it * 2048);
            vp[it] = *(const u32x4*)(Vb + (size_t)it * 131072);
        }

        for (int jt = 0; jt <= qtile; ++jt) {
            __syncthreads();  // all waves done reading previous tile's LDS
#pragma unroll
            for (int it = 0; it < 4; ++it) {
                *(u32x4*)(&Kl[it * 2048 + ldst]) = kp[it];
                *(u32x4*)(&Vl[it * 2048 + ldst]) = vp[it];
            }
            __syncthreads();
            if (jt < qtile) {  // prefetch next tile while this one computes
#pragma unroll
                for (int it = 0; it < 4; ++it) {
                    kp[it] = *(const u32x4*)(Kb + (size_t)(jt + 1) * 8192 + it * 2048);
                    vp[it] = *(const u32x4*)(Vb + (size_t)(jt + 1) * 128 + (size_t)it * 131072);
                }
            }
            const bool diag = (jt == qtile);
            const int jb = jt * 128;

#pragma unroll
            for (int ks2 = 0; ks2 < 4; ++ks2) {
                // --- S (32q x 32k per wave) -> exp2 -> P in LDS ---
#pragma unroll
                for (int f2 = 0; f2 < 2; ++f2) {
                    const int kk = (ks2 * 2 + f2) * 16 + l15;  // key within 128-tile
                    floatx4 sv[2] = {};
#pragma unroll
                    for (int ks = 0; ks < 2; ++ks) {
                        const int c = ks * 4 + quad;
                        short8 kf = *(const short8*)(&Kl[kk * 64 + ((c ^ (l15 & 7)) * 8)]);
                        sv[0] = mfma16(qf[0][ks], kf, sv[0]);
                        sv[1] = mfma16(qf[1][ks], kf, sv[1]);
                    }
#pragma unroll
                    for (int fm = 0; fm < 2; ++fm) {
                        const int qg = qbase + wave * 32 + fm * 16 + quad * 4;
#pragma unroll
                        for (int r = 0; r < 4; ++r) {
                            float e = (diag && (jb + kk > qg + r)) ? 0.f
                                      : __builtin_amdgcn_exp2f(sv[fm][r]);
                            Pl[psb + fm * 576 + r * 36 + f2 * 16] = f2bf_tr(e);
                        }
                    }
                }
                // --- O += P * V; row sums via ones-fragment ---
                short8 pf[2];
#pragma unroll
                for (int fm = 0; fm < 2; ++fm) {
                    pf[fm] = *(const short8*)(&Pl[prb + fm * 576]);
                    lacc[fm] = mfma16(pf[fm], ones, lacc[fm]);
                }
#pragma unroll
                for (int fv = 0; fv < 4; ++fv) {
                    const int hd = fv * 16 + l15;
                    const int c = ks2 * 4 + quad;
                    short8 vf = *(const short8*)(&Vl[hd * 128 + ((c ^ (l15 & 7)) * 8)]);
                    oacc[0][fv] = mfma16(pf[0], vf, oacc[0][fv]);
                    oacc[1][fv] = mfma16(pf[1], vf, oacc[1][fv]);
                }
            }
        }
        // write O (B,N,H,HD); every lane holds full row sums in lacc
#pragma unroll
        for (int fm = 0; fm < 2; ++fm) {
            float lr[4];
#pragma unroll
            for (int r = 0; r < 4; ++r) lr[r] = __builtin_amdgcn_rcpf(lacc[fm][r]);
#pragma unroll
            for (int fv = 0; fv < 4; ++fv)
#pragma unroll
                for (int r = 0; r < 4; ++r) {
                    int qrow = qbase + wave * 32 + fm * 16 + quad * 4 + r;
                    float v = oacc[fm][fv][r] * lr[r];
                    int hd = fv * 16 + l15;
                    uintT u = f2bf(v);
                    uintT pu = (uintT)__shfl_xor((int)u, 1);
                    if (!(l15 & 1)) {
                        size_t idx = (((size_t)(b * 2048 + qrow) * 16 + h) << 6) + hd;
                        *(uintT*)(&O[idx]) = u | (pu << 16);
                    }
                }
        }
    }
}

extern "C" void kernel_launch(void* const* d_in, const int* in_sizes, int n_in,
                              void* d_out, int out_size, void* d_ws, size_t ws_size,
                              hipStream_t stream) {
    const float* x_q  = (const float*)d_in[0];
    const float* x_kv = (const float*)d_in[1];
    const float* pe   = (const float*)d_in[2];
    const float* Wq   = (const float*)d_in[3];
    const float* bq   = (const float*)d_in[4];
    const float* Wk   = (const float*)d_in[5];
    const float* bk   = (const float*)d_in[6];
    const float* Wv   = (const float*)d_in[7];
    const float* bv   = (const float*)d_in[8];
    const float* Wo   = (const float*)d_in[9];
    const float* bo   = (const float*)d_in[10];
    float* out = (float*)d_out;

    char* ws = (char*)d_ws;
    const size_t MB = 1024 * 1024;
    ushortT* xq_bf  = (ushortT*)(ws + 0);
    ushortT* o_ws   = (ushortT*)(ws + 0);   // aliased: xq dead before attn
    ushortT* xkv_bf = (ushortT*)(ws + 16 * MB);
    ushortT* Wqt    = (ushortT*)(ws + 32 * MB);
    ushortT* Wkt    = (ushortT*)(ws + 34 * MB);
    ushortT* Wvt    = (ushortT*)(ws + 36 * MB);
    ushortT* Wot    = (ushortT*)(ws + 38 * MB);
    ushortT* q_ws   = (ushortT*)(ws + 40 * MB);
    ushortT* k_ws   = (ushortT*)(ws + 56 * MB);
    ushortT* v_ws   = (ushortT*)(ws + 72 * MB);

    cvt_bf16_2<<<16384, 256, 0, stream>>>(x_q, x_kv, xq_bf, xkv_bf);
    wtrans<<<dim3(16, 16, 4), 256, 0, stream>>>(Wq, Wk, Wv, Wo, Wqt, Wkt, Wvt, Wot);
    qkv_gemm<<<dim3(512, 3), 256, 0, stream>>>(xq_bf, xkv_bf, Wqt, Wkt, Wvt,
                                               bq, bk, bv, pe, q_ws, k_ws, v_ws);
    attn_fwd<<<dim3(8, 64), 256, 0, stream>>>(q_ws, k_ws, v_ws, o_ws);
    o_gemm<<<dim3(8, 64), 256, 0, stream>>>(o_ws, Wot, bo, out);
}